// Round 12
// baseline (1013.734 us; speedup 1.0000x reference)
//
#include <hip/hip_runtime.h>
#include <hip/hip_bf16.h>

#define Bdim 2
#define Sdim 1024
#define Vdim 32000
#define HDdim 1024
#define Ldim 4
#define Hdim 16
#define Ddim 64
#define Idim 4096
#define BSdim 2048

typedef __attribute__((ext_vector_type(8))) short bf16x8;
typedef __attribute__((ext_vector_type(4))) float f32x4;

__device__ __forceinline__ unsigned short f2bf(float f) {
    __hip_bfloat16 h = __float2bfloat16(f);
    return *reinterpret_cast<unsigned short*>(&h);
}

#define MFMA16(a, b, c) __builtin_amdgcn_mfma_f32_16x16x32_bf16((a), (b), (c), 0, 0, 0)

#define GLD16(gp, lp)                                                            \
    __builtin_amdgcn_global_load_lds((const __attribute__((address_space(1))) void*)(gp), \
                                     (__attribute__((address_space(3))) void*)(lp), 16, 0, 0)

template <int N>
__device__ __forceinline__ void vwait() {
    if constexpr (N == 2) asm volatile("s_waitcnt vmcnt(2)" ::: "memory");
    else if constexpr (N == 3) asm volatile("s_waitcnt vmcnt(3)" ::: "memory");
    else if constexpr (N == 4) asm volatile("s_waitcnt vmcnt(4)" ::: "memory");
    else if constexpr (N == 6) asm volatile("s_waitcnt vmcnt(6)" ::: "memory");
}

// ---------------- init: embedding gather + rope tables (merged) ----------------
__global__ __launch_bounds__(256) void init_kernel(const int* __restrict__ ids, const float* __restrict__ emb,
                                                   float* __restrict__ x, float* __restrict__ cosT,
                                                   float* __restrict__ sinT) {
    int bid = blockIdx.x;
    int tid = threadIdx.x;
    if (bid < BSdim) {
        int id = ids[bid];
        const float4* src = (const float4*)(emb + (size_t)id * HDdim);
        ((float4*)(x + (size_t)bid * HDdim))[tid] = src[tid];
    } else {
        int i = (bid - BSdim) * 256 + tid;   // 65536 = S*D
        int d = i & 63;
        int s = i >> 6;
        float inv = powf(1.0e6f, -((float)(2 * (d & 31))) / 64.0f);
        float f = (float)s * inv;
        cosT[i] = cosf(f);
        sinT[i] = sinf(f);
    }
}

// ---------------- layernorm (+ fused residual-partial reduction, + optional router) ----------------
// a = x[m] + sum_{p<NP} parts[p][m] + badd  ; optionally write a back to xout; LN(a) -> outH
template <int NP>
__global__ __launch_bounds__(256) void ln_kernel(const float* __restrict__ x, float* __restrict__ xout,
                                                 const float* __restrict__ parts, size_t pstride,
                                                 const float* __restrict__ badd,
                                                 const float* __restrict__ w, const float* __restrict__ bw,
                                                 unsigned short* __restrict__ outH,
                                                 const float* __restrict__ Wr, float* __restrict__ routerO) {
    int m = blockIdx.x;
    int tid = threadIdx.x;
    float4 a = ((const float4*)(x + (size_t)m * HDdim))[tid];
    #pragma unroll
    for (int p = 0; p < NP; p++) {
        float4 q = ((const float4*)(parts + p * pstride + (size_t)m * HDdim))[tid];
        a.x += q.x; a.y += q.y; a.z += q.z; a.w += q.w;
    }
    if (badd) {
        float4 bb = ((const float4*)badd)[tid];
        a.x += bb.x; a.y += bb.y; a.z += bb.z; a.w += bb.w;
    }
    if (xout) ((float4*)(xout + (size_t)m * HDdim))[tid] = a;

    float s = a.x + a.y + a.z + a.w;
    #pragma unroll
    for (int o = 1; o < 64; o <<= 1) s += __shfl_xor(s, o);
    __shared__ float red[4], red2[4];
    if ((tid & 63) == 0) red[tid >> 6] = s;
    __syncthreads();
    float mean = (red[0] + red[1] + red[2] + red[3]) * (1.0f / 1024.0f);
    float dx = a.x - mean, dy = a.y - mean, dz = a.z - mean, dw = a.w - mean;
    float s2 = dx * dx + dy * dy + dz * dz + dw * dw;
    #pragma unroll
    for (int o = 1; o < 64; o <<= 1) s2 += __shfl_xor(s2, o);
    if ((tid & 63) == 0) red2[tid >> 6] = s2;
    __syncthreads();
    float var = (red2[0] + red2[1] + red2[2] + red2[3]) * (1.0f / 1024.0f);
    float rs = rsqrtf(var + 1e-6f);
    float4 wv = ((const float4*)w)[tid];
    float4 bv = ((const float4*)bw)[tid];
    float v0 = dx * rs * wv.x + bv.x;
    float v1 = dy * rs * wv.y + bv.y;
    float v2 = dz * rs * wv.z + bv.z;
    float v3 = dw * rs * wv.w + bv.w;
    short4 st = make_short4((short)f2bf(v0), (short)f2bf(v1), (short)f2bf(v2), (short)f2bf(v3));
    *(short4*)(outH + (size_t)m * HDdim + tid * 4) = st;

    if (Wr) {   // fused router: routerO[b][h][s] = h_norm . Wr[:,h]
        __shared__ float rbuf[256][16];
        __shared__ float pbuf[16][17];
        float part[16];
        const float* wr0 = Wr + (size_t)(tid * 4) * Hdim;
        #pragma unroll
        for (int h = 0; h < 16; h++)
            part[h] = v0 * wr0[h] + v1 * wr0[16 + h] + v2 * wr0[32 + h] + v3 * wr0[48 + h];
        #pragma unroll
        for (int h4 = 0; h4 < 4; h4++)
            *(float4*)&rbuf[tid][h4 * 4] = make_float4(part[h4 * 4], part[h4 * 4 + 1], part[h4 * 4 + 2], part[h4 * 4 + 3]);
        __syncthreads();
        {
            int h = tid & 15, g = tid >> 4;
            float sgr = 0.0f;
            #pragma unroll
            for (int i = 0; i < 16; i++) sgr += rbuf[g * 16 + i][h];
            pbuf[g][h] = sgr;
        }
        __syncthreads();
        if (tid < 16) {
            float tot = 0.0f;
            #pragma unroll
            for (int g = 0; g < 16; g++) tot += pbuf[g][tid];
            int b = m >> 10, sI = m & 1023;
            routerO[((size_t)(b * Hdim + tid)) * Sdim + sI] = tot;
        }
    }
}

// ---------------- exact top-k threshold + compacted bias/index ----------------
__global__ __launch_bounds__(1024) void topk_kernel(const float* __restrict__ router, const float* __restrict__ amask,
                                                    float* __restrict__ biasC, int* __restrict__ idxC,
                                                    int* __restrict__ ntA) {
    int bh = blockIdx.x;
    int t = threadIdx.x;
    __shared__ float r[1024];
    __shared__ float kths;
    __shared__ int wcnt[16];
    float v = router[(size_t)bh * Sdim + t];
    r[t] = v;
    __syncthreads();
    int gt = 0, eq = 0;
    for (int j = 0; j < 1024; j++) {
        float xv = r[j];
        gt += (xv > v) ? 1 : 0;
        eq += (xv == v) ? 1 : 0;
    }
    if (gt < 512 && gt + eq >= 512) kths = v;
    // init pad region (ordered before scatter by the barrier below)
    biasC[(size_t)bh * Sdim + t] = -1e9f;
    idxC[(size_t)bh * Sdim + t] = 0;
    __syncthreads();
    float kth = kths;
    bool sel = (v >= kth);
    unsigned long long m = __ballot(sel);
    int wid = t >> 6, lane = t & 63;
    if (lane == 0) wcnt[wid] = __popcll(m);
    __syncthreads();
    int base = 0;
    for (int w = 0; w < wid; w++) base += wcnt[w];
    if (sel) {
        int rank = base + (int)__popcll(m & ((1ull << lane) - 1ull));
        float bias = (v >= 0.0f) ? -log1pf(expf(-v)) : (v - log1pf(expf(v)));
        int b = bh >> 4;
        bias += (1.0f - amask[b * Sdim + t]) * (-1e9f);
        biasC[(size_t)bh * Sdim + rank] = bias;
        idxC[(size_t)bh * Sdim + rank] = t;
    }
    if (t == 0) {
        int tot = 0;
        #pragma unroll
        for (int w = 0; w < 16; w++) tot += wcnt[w];
        ntA[bh] = (tot + 63) >> 6;
    }
}

// ---------------- all weight prepass: 4 x (QKVO + W1 + W2) + lm_head in one dispatch ----------------
__global__ __launch_bounds__(256) void tconv_all(const float* __restrict__ Wq, const float* __restrict__ Wk,
                                                 const float* __restrict__ Wv, const float* __restrict__ Wo,
                                                 const float* __restrict__ W1, const float* __restrict__ W2,
                                                 const float* __restrict__ lmh,
                                                 unsigned short* __restrict__ wtsL,
                                                 unsigned short* __restrict__ wtsLM) {
    const size_t M1 = 1u << 20;
    int bid = blockIdx.x;
    const float* S;
    unsigned short* D;
    int K, ldS, nt, kt;
    if (bid < 49152) {
        int lid = bid / 12288, sub = bid - lid * 12288;
        unsigned short* wl = wtsL + (size_t)lid * 12 * M1;
        if (sub < 4096) {            // QKVO: 4 x [1024][1024]
            int z = sub >> 10, t = sub & 1023;
            S = ((z == 0) ? Wq : (z == 1) ? Wk : (z == 2) ? Wv : Wo) + (size_t)lid * M1;
            D = wl + (size_t)z * M1;
            K = 1024; ldS = 1024; nt = t & 31; kt = t >> 5;
        } else if (sub < 8192) {     // W1: [1024][4096]
            int t = sub - 4096;
            S = W1 + (size_t)lid * 4 * M1; D = wl + 4 * M1;
            K = 1024; ldS = 4096; nt = t % 128; kt = t / 128;
        } else {                     // W2: [4096][1024]
            int t = sub - 8192;
            S = W2 + (size_t)lid * 4 * M1; D = wl + 8 * M1;
            K = 4096; ldS = 1024; nt = t % 32; kt = t / 32;
        }
    } else {                         // lm_head: [1024][32000]
        int t = bid - 49152;
        S = lmh; D = wtsLM;
        K = 1024; ldS = Vdim; nt = t % 1000; kt = t / 1000;
    }
    __shared__ float tb[32][33];
    int ktb = kt * 32, ntb = nt * 32;
    int r = threadIdx.x >> 3, c4 = (threadIdx.x & 7) * 4;
    float4 v = *(const float4*)(S + (size_t)(ktb + r) * ldS + ntb + c4);
    tb[r][c4] = v.x; tb[r][c4 + 1] = v.y; tb[r][c4 + 2] = v.z; tb[r][c4 + 3] = v.w;
    __syncthreads();
    short4 o = make_short4((short)f2bf(tb[c4][r]), (short)f2bf(tb[c4 + 1][r]),
                           (short)f2bf(tb[c4 + 2][r]), (short)f2bf(tb[c4 + 3][r]));
    *(short4*)(D + (size_t)(ntb + r) * K + ktb + c4) = o;
}

// ---------------- compacted V^T gather (XOR swizzle baked in) ----------------
__global__ __launch_bounds__(256) void vgather_kernel(const unsigned short* __restrict__ v16,
                                                      const int* __restrict__ idxC, const int* __restrict__ ntA,
                                                      unsigned short* __restrict__ vTc) {
    int jt = blockIdx.x;        // 16
    int bh = blockIdx.y;        // 32
    if (jt >= ntA[bh]) return;
    __shared__ unsigned short T[64][72];
    int tid = threadIdx.x;
    int jl = tid >> 2;
    int part = tid & 3;
    int j = jt * 64 + jl;
    int src = idxC[(size_t)bh * Sdim + j];
    const unsigned short* vr = v16 + ((size_t)bh * Sdim + src) * Ddim + part * 16;
    *(bf16x8*)&T[jl][part * 16] = *(const bf16x8*)vr;
    *(bf16x8*)&T[jl][part * 16 + 8] = *(const bf16x8*)(vr + 8);
    __syncthreads();
    int d = tid >> 2;
    int xr = (d & 7) << 3;
    unsigned short* dst = vTc + ((size_t)bh * Ddim + d) * Sdim + jt * 64;
    #pragma unroll
    for (int cc = 0; cc < 2; cc++) {
        int tb = (tid & 3) * 16 + cc * 8;
        bf16x8 o;
        #pragma unroll
        for (int i = 0; i < 8; i++) o[i] = (short)T[tb + i][d];
        *(bf16x8*)(dst + (tb ^ xr)) = o;
    }
}

// ================= 8-phase 512-thread MFMA GEMM (T2+T3+T4+T5) =================
// EPI: 1 = fused QKV (rope->bf16), 3 = bias+silu->bf16,
//      5 = plain f32 write at OF + ks*ksStride, 7 = nontemporal f32 write
template <int EPI, int BM, int BN, int WM, int WN>
__global__ __launch_bounds__(512) void gemm8p(
    const unsigned short* __restrict__ A, const unsigned short* __restrict__ Bt,
    float* __restrict__ OF, unsigned short* __restrict__ Hq, unsigned short* __restrict__ Hk,
    unsigned short* __restrict__ Hv, const float* __restrict__ bias,
    const float* __restrict__ cosT, const float* __restrict__ sinT,
    int Kc, int ldK, int ldC, int gridM, int gridN, size_t ksStride) {
    constexpr int MI = BM / WM / 16, NI = BN / WN / 16;
    constexpr int MH = MI / 2, NH = NI / 2;
    constexpr int LA = BM / 128, LB = BN / 128;
    constexpr int HA = BM / WM / 2;   // A half-selector
    constexpr int HB = BN / WN / 2;   // B half-selector
    constexpr int ABUF = BM * 64, BBUF = BN * 64;

    __shared__ unsigned short lds[2 * ABUF + 2 * BBUF];

    int bid = blockIdx.x;
    const int nwg = gridDim.x;
    if ((nwg & 7) == 0) bid = (bid & 7) * (nwg >> 3) + (bid >> 3);   // XCD swizzle (bijective: nwg%8==0)
    const int mn = gridM * gridN;
    const int ks = bid / mn;
    const int rem = bid - ks * mn;
    const int bm = (rem % gridM) * BM;
    const int bn = (rem / gridM) * BN;
    const unsigned short* Ap = A + (size_t)ks * Kc;
    const unsigned short* Bp = Bt + (size_t)ks * Kc;

    const int tid = threadIdx.x;
    const int lane = tid & 63, wid = tid >> 6;
    const int lc = lane & 15, lg = lane >> 4;
    const int wwm = wid / WN, wwn = wid % WN;

    const int srow = tid >> 3;                    // 0..63
    const int scol = ((tid & 7) ^ (srow & 7)) * 8;
    const int ak0 = (lg * 8) ^ ((lc & 7) * 8);
    const int ak1 = (32 + lg * 8) ^ ((lc & 7) * 8);

    f32x4 acc[MI][NI];
    f32x4 zero = {0.0f, 0.0f, 0.0f, 0.0f};
    #pragma unroll
    for (int i = 0; i < MI; i++)
        #pragma unroll
        for (int j = 0; j < NI; j++) acc[i][j] = zero;

    bf16x8 a[MH][2], b0[NH][2], b1[NH][2];

    auto stage_a = [&](int half, int nbuf, int kt) {
        #pragma unroll
        for (int j = 0; j < LA; j++) {
            const int idx = j * 64 + srow;                          // [0, BM/2)
            const int grow = (idx / HA) * (BM / WM) + half * HA + (idx % HA);
            const unsigned short* g = Ap + (size_t)(bm + grow) * ldK + kt + scol;
            GLD16(g, &lds[nbuf * ABUF + half * (ABUF / 2) + (j * 512 + tid) * 8]);
        }
    };
    auto stage_b = [&](int half, int nbuf, int kt) {
        #pragma unroll
        for (int j = 0; j < LB; j++) {
            const int idx = j * 64 + srow;                          // [0, BN/2)
            const int grow = (idx / HB) * (BN / WN) + half * HB + (idx % HB);
            const unsigned short* g = Bp + (size_t)(bn + grow) * ldK + kt + scol;
            GLD16(g, &lds[2 * ABUF + nbuf * BBUF + half * (BBUF / 2) + (j * 512 + tid) * 8]);
        }
    };

#define DS_A(mh_, cur_)                                                                   \
    _Pragma("unroll") for (int m = 0; m < MH; m++) {                                      \
        const int ro = (cur_)*ABUF + (mh_) * (ABUF / 2) + (wwm * HA + m * 16 + lc) * 64;  \
        a[m][0] = *(const bf16x8*)&lds[ro + ak0];                                         \
        a[m][1] = *(const bf16x8*)&lds[ro + ak1];                                         \
    }
#define DS_B(bb_, nh_, cur_)                                                              \
    _Pragma("unroll") for (int n = 0; n < NH; n++) {                                      \
        const int ro = 2 * ABUF + (cur_)*BBUF + (nh_) * (BBUF / 2) + (wwn * HB + n * 16 + lc) * 64; \
        bb_[n][0] = *(const bf16x8*)&lds[ro + ak0];                                       \
        bb_[n][1] = *(const bf16x8*)&lds[ro + ak1];                                       \
    }
#define MFMA_PH(mh_, nh_, bb_)                                                            \
    __builtin_amdgcn_s_setprio(1);                                                        \
    _Pragma("unroll") for (int m = 0; m < MH; m++) _Pragma("unroll") for (int n = 0; n < NH; n++) { \
        acc[(mh_)*MH + m][(nh_)*NH + n] = MFMA16(a[m][0], bb_[n][0], acc[(mh_)*MH + m][(nh_)*NH + n]); \
        acc[(mh_)*MH + m][(nh_)*NH + n] = MFMA16(a[m][1], bb_[n][1], acc[(mh_)*MH + m][(nh_)*NH + n]); \
    }                                                                                     \
    __builtin_amdgcn_s_setprio(0);
#define BAR_PRE()                                                                         \
    __builtin_amdgcn_sched_barrier(0);                                                    \
    __builtin_amdgcn_s_barrier();
#define BAR_END()                                                                         \
    asm volatile("" ::: "memory");                                                        \
    __builtin_amdgcn_s_barrier();                                                         \
    __builtin_amdgcn_sched_barrier(0);

    // prologue: tile 0 half-tiles in steady-state order; leave {Bh1,Ah1} in flight
    stage_a(0, 0, 0);
    stage_b(0, 0, 0);
    stage_b(1, 0, 0);
    stage_a(1, 0, 0);
    vwait<LA + LB>();
    BAR_END();

    const int NT = Kc >> 6;
    for (int t = 0; t < NT; t++) {
        const int cur = t & 1, nxt = cur ^ 1;
        const int ktn = (t + 1 < NT) ? (t + 1) * 64 : t * 64;
        // phase 1: quadrant (0,0)
        DS_A(0, cur);
        DS_B(b0, 0, cur);
        stage_a(0, nxt, ktn);
        BAR_PRE();
        MFMA_PH(0, 0, b0);
        vwait<2 * LA>();            // completes B_h1(cur)
        BAR_END();
        // phase 2: quadrant (0,1)
        DS_B(b1, 1, cur);
        stage_b(0, nxt, ktn);
        BAR_PRE();
        MFMA_PH(0, 1, b1);
        vwait<LA + LB>();           // completes A_h1(cur)
        BAR_END();
        // phase 3: quadrant (1,1)
        DS_A(1, cur);
        stage_b(1, nxt, ktn);
        BAR_PRE();
        MFMA_PH(1, 1, b1);
        BAR_END();
        // phase 4: quadrant (1,0)
        stage_a(1, nxt, ktn);
        BAR_PRE();
        MFMA_PH(1, 0, b0);
        vwait<LA + LB>();           // completes A_h0, B_h0 of nxt
        BAR_END();
    }
    asm volatile("s_waitcnt vmcnt(0)" ::: "memory");   // drain LDS-destined loads before endpgm
#undef DS_A
#undef DS_B
#undef MFMA_PH
#undef BAR_PRE
#undef BAR_END

    // epilogue. D frag layout: row = lg*4 + r, col = lc
    #pragma unroll
    for (int i = 0; i < MI; i++) {
        if (EPI == 1) {
            const int colbase = bn + wwn * (BN / WN);
            const int zc = colbase >> 10;                 // 0=q 1=k 2=v
            unsigned short* OH = (zc == 0) ? Hq : (zc == 1) ? Hk : Hv;
            const int hcol = (colbase >> 6) & 15;
            #pragma unroll
            for (int r = 0; r < 4; r++) {
                int row = bm + wwm * (BM / WM) + i * 16 + lg * 4 + r;
                int b = row >> 10, s = row & 1023;
                size_t base = ((size_t)(b * Hdim + hcol) * Sdim + s) << 6;
                if (zc == 2) {
                    #pragma unroll
                    for (int j = 0; j < 4; j++) OH[base + j * 16 + lc] = f2bf(acc[i][j][r]);
                } else {
                    #pragma unroll
                    for (int j = 0; j < 2; j++) {
                        int d = j * 16 + lc;              // [0,32)
                        float x1 = acc[i][j][r];
                        float x2 = acc[i][j + 2][r];
                        float c = cosT[s * 64 + d];
                        float sn = sinT[s * 64 + d];
                        OH[base + d] = f2bf(x1 * c - x2 * sn);
                        OH[base + d + 32] = f2bf(x2 * c + x1 * sn);
                    }
                }
            }
        } else {
            float* OFk = OF + (size_t)ks * ksStride;
            #pragma unroll
            for (int r = 0; r < 4; r++) {
                int row = bm + wwm * (BM / WM) + i * 16 + lg * 4 + r;
                #pragma unroll
                for (int j = 0; j < NI; j++) {
                    int col = bn + wwn * (BN / WN) + j * 16 + lc;
                    float v = acc[i][j][r];
                    if (EPI == 3) {
                        float t = v + bias[col];
                        Hq[(size_t)row * ldC + col] = f2bf(t / (1.0f + expf(-t)));
                    } else if (EPI == 7) {
                        __builtin_nontemporal_store(v, &OFk[(size_t)row * ldC + col]);
                    } else {
                        OFk[(size_t)row * ldC + col] = v;
                    }
                }
            }
        }
    }
}

// ---------------- flash attention over compacted keys (routed bias) ----------------
// QBLK=128: 8 waves x 16 q-rows; K gathered in-LDS-stage via idxC; V^T pre-gathered.
// T13 defer-max: skip O-rescale when the whole wave's tile-max growth <= 8.
__global__ __launch_bounds__(512) void attn_kernel(const unsigned short* __restrict__ q16,
                                                   const unsigned short* __restrict__ k16,
                                                   const unsigned short* __restrict__ vTc,
                                                   const int* __restrict__ idxC,
                                                   const float* __restrict__ biasC,
                                                   const int* __restrict__ ntA,
                                                   unsigned short* __restrict__ o16) {
    const int qb = blockIdx.x;   // 8 (128 q rows each)
    const int bh = blockIdx.y;   // 32
    const int tid = threadIdx.x;
    const int w = tid >> 6, lane = tid & 63;
    const int lg = lane >> 4, lc = lane & 15;
    const int nt = ntA[bh];

    __shared__ unsigned short Ks[2][64 * 64];
    __shared__ unsigned short Vs[2][64 * 64];
    __shared__ unsigned short Pq[8][16][72];
    __shared__ float sbAll[1024];

    {
        const float2 bv = ((const float2*)(biasC + (size_t)bh * Sdim))[tid];
        *(float2*)&sbAll[tid * 2] = bv;
    }

    const int qrow = qb * 128 + w * 16 + lc;
    const unsigned short* qbase = q16 + ((size_t)bh * Sdim + qrow) * Ddim;
    bf16x8 qf[2];
    qf[0] = *(const bf16x8*)(qbase + lg * 8);
    qf[1] = *(const bf16x8*)(qbase + 32 + lg * 8);

    const int grow = tid >> 3;                 // 0..63
    const int gc = (tid & 7) * 8;
    const int ksw = (grow & 7) << 3;           // K source-col swizzle
    const unsigned short* kbase = k16 + (size_t)bh * Sdim * Ddim;
    const int* ibase = idxC + (size_t)bh * Sdim;
    const unsigned short* vbase = vTc + (size_t)bh * Ddim * Sdim;

    auto stageKV = [&](int buf, int t1) {
        int s0 = ibase[t1 + grow];
        GLD16(kbase + (size_t)s0 * Ddim + (gc ^ ksw), &Ks[buf][tid * 8]);
        GLD16(vbase + (size_t)grow * Sdim + t1 + gc, &Vs[buf][tid * 8]);
    };

    stageKV(0, 0);
    __syncthreads();

    float m_i = -1e30f, l_i = 0.0f;
    f32x4 ot[4];
    f32x4 zero = {0.0f, 0.0f, 0.0f, 0.0f};
    #pragma unroll
    for (int fd = 0; fd < 4; fd++) ot[fd] = zero;

    const int sw = (lc & 7) << 3;

    for (int tt = 0; tt < nt; tt++) {
        const int cur = tt & 1;
        if (tt > 0) {
            asm volatile("s_waitcnt vmcnt(0)" ::: "memory");
            __builtin_amdgcn_sched_barrier(0);
            __builtin_amdgcn_s_barrier();
        }
        if (tt < nt - 1) {
            stageKV(cur ^ 1, (tt + 1) * 64);
        }

        f32x4 sf[4];
        #pragma unroll
        for (int f = 0; f < 4; f++) {
            const int trow = f * 16 + lc;
            f32x4 a = zero;
            #pragma unroll
            for (int ks = 0; ks < 2; ks++) {
                bf16x8 kfr = *(bf16x8*)&Ks[cur][trow * 64 + ((ks * 32 + lg * 8) ^ sw)];
                a = MFMA16(kfr, qf[ks], a);
            }
            sf[f] = a;
        }
        const int t0 = tt * 64;
        float tmax = -1e30f;
        #pragma unroll
        for (int f = 0; f < 4; f++)
            #pragma unroll
            for (int j = 0; j < 4; j++) {
                float v = sf[f][j] * 0.125f + sbAll[t0 + f * 16 + lg * 4 + j];
                sf[f][j] = v;
                tmax = fmaxf(tmax, v);
            }
        tmax = fmaxf(tmax, __shfl_xor(tmax, 16));
        tmax = fmaxf(tmax, __shfl_xor(tmax, 32));
        // T13 defer-max: rescale only when some lane's max grew by > 8
        if (!__all(tmax - m_i <= 8.0f)) {
            float mnew = fmaxf(m_i, tmax);
            float alpha = expf(m_i - mnew);
            l_i *= alpha;
            #pragma unroll
            for (int fd = 0; fd < 4; fd++)
                #pragma unroll
                for (int j = 0; j < 4; j++) ot[fd][j] *= alpha;
            m_i = mnew;
        }
        float lsum = 0.0f;
        #pragma unroll
        for (int f = 0; f < 4; f++)
            #pragma unroll
            for (int j = 0; j < 4; j++) {
                float p = expf(sf[f][j] - m_i);
                sf[f][j] = p;
                lsum += p;
            }
        lsum += __shfl_xor(lsum, 16);
        lsum += __shfl_xor(lsum, 32);
        l_i += lsum;
        #pragma unroll
        for (int f = 0; f < 4; f++) {
            short4 ps = make_short4((short)f2bf(sf[f][0]), (short)f2bf(sf[f][1]),
                                    (short)f2bf(sf[f][2]), (short)f2bf(sf[f][3]));
            *(short4*)&Pq[w][lc][f * 16 + lg * 4] = ps;
        }
        #pragma unroll
        for (int ks = 0; ks < 2; ks++) {
            bf16x8 pf = *(bf16x8*)&Pq[w][lc][ks * 32 + lg * 8];
            #pragma unroll
            for (int fd = 0; fd < 4; fd++) {
                bf16x8 vfr = *(bf16x8*)&Vs[cur][(fd * 16 + lc) * 64 + ((ks * 32 + lg * 8) ^ sw)];
                ot[fd] = MFMA16(vfr, pf, ot[fd]);
            }
        }
    }
    asm volatile("s_waitcnt vmcnt(0)" ::: "memory");   // drain LDS-destined loads before endpgm
    float rl = 1.0f / l_i;
    int b = bh >> 4, h = bh & 15;
    #pragma unroll
    for (int fd = 0; fd < 4; fd++)
        #pragma unroll
        for (int j = 0; j < 4; j++) {
            int d = fd * 16 + lg * 4 + j;
            o16[((size_t)b * Sdim + qrow) * HDdim + h * 64 + d] = f2bf(ot[fd][j] * rl);
        }
}

extern "C" void kernel_launch(void* const* d_in, const int* in_sizes, int n_in,
                              void* d_out, int out_size, void* d_ws, size_t ws_size,
                              hipStream_t stream) {
    const int* ids = (const int*)d_in[0];
    const float* amask = (const float*)d_in[1];
    const float* emb = (const float*)d_in[2];
    const float* ln1w = (const float*)d_in[3];
    const float* ln1b = (const float*)d_in[4];
    const float* Wq = (const float*)d_in[5];
    const float* Wk = (const float*)d_in[6];
    const float* Wv = (const float*)d_in[7];
    const float* Wo = (const float*)d_in[8];
    const float* Wr = (const float*)d_in[9];
    const float* ln2w = (const float*)d_in[10];
    const float* ln2b = (const float*)d_in[11];
    const float* W1 = (const float*)d_in[12];
    const float* b1 = (const float*)d_in[13];
    const float* W2 = (const float*)d_in[14];
    const float* b2 = (const float*)d_in[15];
    const float* nw = (const float*)d_in[16];
    const float* nb = (const float*)d_in[17];
    const float* lmh = (const float*)d_in[18];
    float* out = (float*)d_out;

    char* p = (char*)d_ws;
    size_t off = 0;
    auto alloc = [&](size_t bytes) -> void* {
        void* r = p + off;
        off += (bytes + 255) & ~(size_t)255;
        return r;
    };
    float* cosT = (float*)alloc((size_t)Sdim * Ddim * 4);
    float* sinT = (float*)alloc((size_t)Sdim * Ddim * 4);
    float* x = (float*)alloc((size_t)BSdim * HDdim * 4);
    unsigned short* h16 = (unsigned short*)alloc((size_t)BSdim * HDdim * 2);
    unsigned short* o16 = (unsigned short*)alloc((size_t)BSdim * HDdim * 2);
    unsigned short* m16 = (unsigned short*)alloc((size_t)BSdim * Idim * 2);
    unsigned short* q16 = (unsigned short*)alloc((size_t)Bdim * Hdim * Sdim * Ddim * 2);
    unsigned short* k16 = (unsigned short*)alloc((size_t)Bdim * Hdim * Sdim * Ddim * 2);
    unsigned short* v16 = (unsigned short*)alloc((size_t)Bdim * Hdim * Sdim * Ddim * 2);
    unsigned short* vTc = (unsigned short*)alloc((size_t)Bdim * Hdim * Sdim * Ddim * 2);
    float* router = (float*)alloc((size_t)Bdim * Hdim * Sdim * 4);
    float* biasC = (float*)alloc((size_t)Bdim * Hdim * Sdim * 4);
    int* idxC = (int*)alloc((size_t)Bdim * Hdim * Sdim * 4);
    int* ntA = (int*)alloc((size_t)Bdim * Hdim * 4);
    float* po = (float*)alloc((size_t)2 * BSdim * HDdim * 4);   // Wo split-K partials
    float* pw = (float*)alloc((size_t)4 * BSdim * HDdim * 4);   // W2 split-K partials
    unsigned short* wts = (unsigned short*)alloc((size_t)Vdim * HDdim * 2);        // 64MB lm_head
    unsigned short* wtsL = (unsigned short*)alloc((size_t)Ldim * 12 * (1u << 20) * 2);  // 96MB layer weights

    const size_t M1 = 1u << 20;  // 1M elems
    const size_t PS = (size_t)BSdim * HDdim;

    init_kernel<<<BSdim + 256, 256, 0, stream>>>(ids, emb, x, cosT, sinT);
    tconv_all<<<49152 + 32000, 256, 0, stream>>>(Wq, Wk, Wv, Wo, W1, W2, lmh, wtsL, wts);

    for (int l = 0; l < Ldim; l++) {
        unsigned short* wl = wtsL + (size_t)l * 12 * M1;
        const float* Wr_l = Wr + (size_t)l * HDdim * Hdim;
        const float* b1_l = b1 + (size_t)l * Idim;
        const float* b2_l = b2 + (size_t)l * HDdim;

        // ln1 (+fused router). For l>0 it also folds in prev layer's W2 partials + b2.
        if (l == 0)
            ln_kernel<0><<<BSdim, 256, 0, stream>>>(x, nullptr, nullptr, 0, nullptr,
                                                    ln1w + l * HDdim, ln1b + l * HDdim, h16, Wr_l, router);
        else
            ln_kernel<4><<<BSdim, 256, 0, stream>>>(x, x, pw, PS, b2 + (size_t)(l - 1) * HDdim,
                                                    ln1w + l * HDdim, ln1b + l * HDdim, h16, Wr_l, router);
        topk_kernel<<<Bdim * Hdim, 1024, 0, stream>>>(router, amask, biasC, idxC, ntA);
        // fused QKV GEMM (8-phase, 128x128): grid 16 x 24 = 384
        gemm8p<1, 128, 128, 4, 2><<<384, 512, 0, stream>>>(h16, wl, nullptr, q16, k16, v16,
                                                           nullptr, cosT, sinT, HDdim, HDdim, 0, 16, 24, 0);
        // compacted V^T gather; K gathered in-attn
        vgather_kernel<<<dim3(16, 32), 256, 0, stream>>>(v16, idxC, ntA, vTc);
        // attention: QBLK=128, 8 waves
        attn_kernel<<<dim3(8, 32), 512, 0, stream>>>(q16, k16, vTc, idxC, biasC, ntA, o16);
        // Wo GEMM (split-K=2 partial buffers): grid 16 x 8 x 2 = 256
        gemm8p<5, 128, 128, 4, 2><<<256, 512, 0, stream>>>(o16, wl + 3 * M1, po, nullptr, nullptr, nullptr,
                                                           nullptr, nullptr, nullptr, 512, HDdim, HDdim, 16, 8, PS);
        // ln2 folds in Wo partials (x += po0+po1) and LNs the result
        ln_kernel<2><<<BSdim, 256, 0, stream>>>(x, x, po, PS, nullptr,
                                                ln2w + l * HDdim, ln2b + l * HDdim, h16, nullptr, nullptr);
        // W1 GEMM (bias+silu): grid 16 x 32 = 512
        gemm8p<3, 128, 128, 4, 2><<<512, 512, 0, stream>>>(h16, wl + 4 * M1, nullptr, m16, nullptr, nullptr,
                                                           b1_l, nullptr, nullptr, HDdim, HDdim, Idim, 16, 32, 0);
        // W2 GEMM (split-K=4 partial buffers): grid 16 x 8 x 4 = 512
        gemm8p<5, 128, 128, 4, 2><<<512, 512, 0, stream>>>(m16, wl + 8 * M1, pw, nullptr, nullptr, nullptr,
                                                           nullptr, nullptr, nullptr, 1024, Idim, HDdim, 16, 8, PS);
    }

    // final ln folds in last layer's W2 partials + b2
    ln_kernel<4><<<BSdim, 256, 0, stream>>>(x, nullptr, pw, PS, b2 + (size_t)3 * HDdim,
                                            nw, nb, h16, nullptr, nullptr);
    // lm_head: 128x128 tile (64KB LDS -> 2 blocks/CU so epilogue overlaps K-loop),
    // nt stores keep the 262MB f32 output stream from evicting B-panels (round-8 failure mechanism)
    gemm8p<7, 128, 128, 4, 2><<<4000, 512, 0, stream>>>(h16, wts, out, nullptr, nullptr, nullptr,
                                                        nullptr, nullptr, nullptr, HDdim, HDdim, Vdim, 16, 250, 0);
}

// Round 13
// 873.014 us; speedup vs baseline: 1.1612x; 1.1612x over previous
//
#include <hip/hip_runtime.h>
#include <hip/hip_bf16.h>

#define Bdim 2
#define Sdim 1024
#define Vdim 32000
#define HDdim 1024
#define Ldim 4
#define Hdim 16
#define Ddim 64
#define Idim 4096
#define BSdim 2048

typedef __attribute__((ext_vector_type(8))) short bf16x8;
typedef __attribute__((ext_vector_type(4))) float f32x4;

__device__ __forceinline__ unsigned short f2bf(float f) {
    __hip_bfloat16 h = __float2bfloat16(f);
    return *reinterpret_cast<unsigned short*>(&h);
}

#define MFMA16(a, b, c) __builtin_amdgcn_mfma_f32_16x16x32_bf16((a), (b), (c), 0, 0, 0)

#define GLD16(gp, lp)                                                            \
    __builtin_amdgcn_global_load_lds((const __attribute__((address_space(1))) void*)(gp), \
                                     (__attribute__((address_space(3))) void*)(lp), 16, 0, 0)

template <int N>
__device__ __forceinline__ void vwait() {
    if constexpr (N == 2) asm volatile("s_waitcnt vmcnt(2)" ::: "memory");
    else if constexpr (N == 3) asm volatile("s_waitcnt vmcnt(3)" ::: "memory");
    else if constexpr (N == 4) asm volatile("s_waitcnt vmcnt(4)" ::: "memory");
    else if constexpr (N == 6) asm volatile("s_waitcnt vmcnt(6)" ::: "memory");
}

// ---------------- init: embedding gather + rope tables (merged) ----------------
__global__ __launch_bounds__(256) void init_kernel(const int* __restrict__ ids, const float* __restrict__ emb,
                                                   float* __restrict__ x, float* __restrict__ cosT,
                                                   float* __restrict__ sinT) {
    int bid = blockIdx.x;
    int tid = threadIdx.x;
    if (bid < BSdim) {
        int id = ids[bid];
        const float4* src = (const float4*)(emb + (size_t)id * HDdim);
        ((float4*)(x + (size_t)bid * HDdim))[tid] = src[tid];
    } else {
        int i = (bid - BSdim) * 256 + tid;   // 65536 = S*D
        int d = i & 63;
        int s = i >> 6;
        float inv = powf(1.0e6f, -((float)(2 * (d & 31))) / 64.0f);
        float f = (float)s * inv;
        cosT[i] = cosf(f);
        sinT[i] = sinf(f);
    }
}

// ---------------- layernorm (+ fused residual-partial reduction, + optional router) ----------------
// a = x[m] + sum_{p<NP} parts[p][m] + badd  ; optionally write a back to xout; LN(a) -> outH
template <int NP>
__global__ __launch_bounds__(256) void ln_kernel(const float* __restrict__ x, float* __restrict__ xout,
                                                 const float* __restrict__ parts, size_t pstride,
                                                 const float* __restrict__ badd,
                                                 const float* __restrict__ w, const float* __restrict__ bw,
                                                 unsigned short* __restrict__ outH,
                                                 const float* __restrict__ Wr, float* __restrict__ routerO) {
    int m = blockIdx.x;
    int tid = threadIdx.x;
    float4 a = ((const float4*)(x + (size_t)m * HDdim))[tid];
    #pragma unroll
    for (int p = 0; p < NP; p++) {
        float4 q = ((const float4*)(parts + p * pstride + (size_t)m * HDdim))[tid];
        a.x += q.x; a.y += q.y; a.z += q.z; a.w += q.w;
    }
    if (badd) {
        float4 bb = ((const float4*)badd)[tid];
        a.x += bb.x; a.y += bb.y; a.z += bb.z; a.w += bb.w;
    }
    if (xout) ((float4*)(xout + (size_t)m * HDdim))[tid] = a;

    float s = a.x + a.y + a.z + a.w;
    #pragma unroll
    for (int o = 1; o < 64; o <<= 1) s += __shfl_xor(s, o);
    __shared__ float red[4], red2[4];
    if ((tid & 63) == 0) red[tid >> 6] = s;
    __syncthreads();
    float mean = (red[0] + red[1] + red[2] + red[3]) * (1.0f / 1024.0f);
    float dx = a.x - mean, dy = a.y - mean, dz = a.z - mean, dw = a.w - mean;
    float s2 = dx * dx + dy * dy + dz * dz + dw * dw;
    #pragma unroll
    for (int o = 1; o < 64; o <<= 1) s2 += __shfl_xor(s2, o);
    if ((tid & 63) == 0) red2[tid >> 6] = s2;
    __syncthreads();
    float var = (red2[0] + red2[1] + red2[2] + red2[3]) * (1.0f / 1024.0f);
    float rs = rsqrtf(var + 1e-6f);
    float4 wv = ((const float4*)w)[tid];
    float4 bv = ((const float4*)bw)[tid];
    float v0 = dx * rs * wv.x + bv.x;
    float v1 = dy * rs * wv.y + bv.y;
    float v2 = dz * rs * wv.z + bv.z;
    float v3 = dw * rs * wv.w + bv.w;
    short4 st = make_short4((short)f2bf(v0), (short)f2bf(v1), (short)f2bf(v2), (short)f2bf(v3));
    *(short4*)(outH + (size_t)m * HDdim + tid * 4) = st;

    if (Wr) {   // fused router: routerO[b][h][s] = h_norm . Wr[:,h]
        __shared__ float rbuf[256][16];
        __shared__ float pbuf[16][17];
        float part[16];
        const float* wr0 = Wr + (size_t)(tid * 4) * Hdim;
        #pragma unroll
        for (int h = 0; h < 16; h++)
            part[h] = v0 * wr0[h] + v1 * wr0[16 + h] + v2 * wr0[32 + h] + v3 * wr0[48 + h];
        #pragma unroll
        for (int h4 = 0; h4 < 4; h4++)
            *(float4*)&rbuf[tid][h4 * 4] = make_float4(part[h4 * 4], part[h4 * 4 + 1], part[h4 * 4 + 2], part[h4 * 4 + 3]);
        __syncthreads();
        {
            int h = tid & 15, g = tid >> 4;
            float sgr = 0.0f;
            #pragma unroll
            for (int i = 0; i < 16; i++) sgr += rbuf[g * 16 + i][h];
            pbuf[g][h] = sgr;
        }
        __syncthreads();
        if (tid < 16) {
            float tot = 0.0f;
            #pragma unroll
            for (int g = 0; g < 16; g++) tot += pbuf[g][tid];
            int b = m >> 10, sI = m & 1023;
            routerO[((size_t)(b * Hdim + tid)) * Sdim + sI] = tot;
        }
    }
}

// ---------------- top-k threshold via 4-pass radix select + compacted bias/index ----------------
__global__ __launch_bounds__(1024) void topk_kernel(const float* __restrict__ router, const float* __restrict__ amask,
                                                    float* __restrict__ biasC, int* __restrict__ idxC,
                                                    int* __restrict__ ntA) {
    int bh = blockIdx.x;
    int t = threadIdx.x;
    __shared__ unsigned hist[256];
    __shared__ int wcnt[16];
    __shared__ int rankS, dSel, rNew;
    __shared__ unsigned kthS;

    float v = router[(size_t)bh * Sdim + t];
    unsigned fb = __float_as_uint(v);
    unsigned key = fb ^ ((unsigned)(((int)fb) >> 31) | 0x80000000u);   // monotonic: bigger float -> bigger key

    if (t == 0) { rankS = 512; kthS = 0u; }
    // init pad region (ordered before scatter by the barriers below)
    biasC[(size_t)bh * Sdim + t] = -1e9f;
    idxC[(size_t)bh * Sdim + t] = 0;
    bool active = true;
    __syncthreads();

    #pragma unroll
    for (int pass = 3; pass >= 0; pass--) {
        if (t < 256) hist[t] = 0u;
        __syncthreads();
        int dig = (int)((key >> (pass * 8)) & 255u);
        if (active) atomicAdd(&hist[dig], 1u);
        __syncthreads();
        if (t < 64) {   // wave 0: suffix-scan 256 bins (4 per lane) + pick digit at rank
            unsigned h0 = hist[t * 4], h1 = hist[t * 4 + 1], h2 = hist[t * 4 + 2], h3 = hist[t * 4 + 3];
            unsigned lt = h0 + h1 + h2 + h3;
            unsigned suf = lt;
            #pragma unroll
            for (int off = 1; off < 64; off <<= 1) {
                unsigned o = __shfl_down(suf, off);
                if (t + off < 64) suf += o;
            }
            unsigned sufNext = suf - lt;              // count of keys in bins > lane's top bin
            int r = rankS;
            unsigned a3 = sufNext, a2 = a3 + h3, a1 = a2 + h2, a0 = a1 + h1;
            if ((int)a0 < r && r <= (int)(a0 + h0)) { dSel = t * 4 + 0; rNew = r - (int)a0; }
            if ((int)a1 < r && r <= (int)(a1 + h1)) { dSel = t * 4 + 1; rNew = r - (int)a1; }
            if ((int)a2 < r && r <= (int)(a2 + h2)) { dSel = t * 4 + 2; rNew = r - (int)a2; }
            if ((int)a3 < r && r <= (int)(a3 + h3)) { dSel = t * 4 + 3; rNew = r - (int)a3; }
        }
        __syncthreads();
        int ds = dSel;
        active = active && (dig == ds);
        if (t == 0) { kthS |= (unsigned)ds << (pass * 8); rankS = rNew; }
        __syncthreads();
    }

    bool sel = (key >= kthS);                          // == (v >= kth), kth bitwise exact
    unsigned long long m = __ballot(sel);
    int wid = t >> 6, lane = t & 63;
    if (lane == 0) wcnt[wid] = __popcll(m);
    __syncthreads();
    int base = 0;
    for (int w = 0; w < wid; w++) base += wcnt[w];
    if (sel) {
        int rank = base + (int)__popcll(m & ((1ull << lane) - 1ull));
        float bias = (v >= 0.0f) ? -log1pf(expf(-v)) : (v - log1pf(expf(v)));
        int b = bh >> 4;
        bias += (1.0f - amask[b * Sdim + t]) * (-1e9f);
        biasC[(size_t)bh * Sdim + rank] = bias;
        idxC[(size_t)bh * Sdim + rank] = t;
    }
    if (t == 0) {
        int tot = 0;
        #pragma unroll
        for (int w = 0; w < 16; w++) tot += wcnt[w];
        ntA[bh] = (tot + 63) >> 6;
    }
}

// ---------------- all weight prepass: 4 x (QKVO + W1 + W2) + lm_head in one dispatch ----------------
__global__ __launch_bounds__(256) void tconv_all(const float* __restrict__ Wq, const float* __restrict__ Wk,
                                                 const float* __restrict__ Wv, const float* __restrict__ Wo,
                                                 const float* __restrict__ W1, const float* __restrict__ W2,
                                                 const float* __restrict__ lmh,
                                                 unsigned short* __restrict__ wtsL,
                                                 unsigned short* __restrict__ wtsLM) {
    const size_t M1 = 1u << 20;
    int bid = blockIdx.x;
    const float* S;
    unsigned short* D;
    int K, ldS, nt, kt;
    if (bid < 49152) {
        int lid = bid / 12288, sub = bid - lid * 12288;
        unsigned short* wl = wtsL + (size_t)lid * 12 * M1;
        if (sub < 4096) {            // QKVO: 4 x [1024][1024]
            int z = sub >> 10, t = sub & 1023;
            S = ((z == 0) ? Wq : (z == 1) ? Wk : (z == 2) ? Wv : Wo) + (size_t)lid * M1;
            D = wl + (size_t)z * M1;
            K = 1024; ldS = 1024; nt = t & 31; kt = t >> 5;
        } else if (sub < 8192) {     // W1: [1024][4096]
            int t = sub - 4096;
            S = W1 + (size_t)lid * 4 * M1; D = wl + 4 * M1;
            K = 1024; ldS = 4096; nt = t % 128; kt = t / 128;
        } else {                     // W2: [4096][1024]
            int t = sub - 8192;
            S = W2 + (size_t)lid * 4 * M1; D = wl + 8 * M1;
            K = 4096; ldS = 1024; nt = t % 32; kt = t / 32;
        }
    } else {                         // lm_head: [1024][32000]
        int t = bid - 49152;
        S = lmh; D = wtsLM;
        K = 1024; ldS = Vdim; nt = t % 1000; kt = t / 1000;
    }
    __shared__ float tb[32][33];
    int ktb = kt * 32, ntb = nt * 32;
    int r = threadIdx.x >> 3, c4 = (threadIdx.x & 7) * 4;
    float4 v = *(const float4*)(S + (size_t)(ktb + r) * ldS + ntb + c4);
    tb[r][c4] = v.x; tb[r][c4 + 1] = v.y; tb[r][c4 + 2] = v.z; tb[r][c4 + 3] = v.w;
    __syncthreads();
    short4 o = make_short4((short)f2bf(tb[c4][r]), (short)f2bf(tb[c4 + 1][r]),
                           (short)f2bf(tb[c4 + 2][r]), (short)f2bf(tb[c4 + 3][r]));
    *(short4*)(D + (size_t)(ntb + r) * K + ktb + c4) = o;
}

// ---------------- compacted V^T gather (XOR swizzle baked in) ----------------
__global__ __launch_bounds__(256) void vgather_kernel(const unsigned short* __restrict__ v16,
                                                      const int* __restrict__ idxC, const int* __restrict__ ntA,
                                                      unsigned short* __restrict__ vTc) {
    int jt = blockIdx.x;        // 16
    int bh = blockIdx.y;        // 32
    if (jt >= ntA[bh]) return;
    __shared__ unsigned short T[64][72];
    int tid = threadIdx.x;
    int jl = tid >> 2;
    int part = tid & 3;
    int j = jt * 64 + jl;
    int src = idxC[(size_t)bh * Sdim + j];
    const unsigned short* vr = v16 + ((size_t)bh * Sdim + src) * Ddim + part * 16;
    *(bf16x8*)&T[jl][part * 16] = *(const bf16x8*)vr;
    *(bf16x8*)&T[jl][part * 16 + 8] = *(const bf16x8*)(vr + 8);
    __syncthreads();
    int d = tid >> 2;
    int xr = (d & 7) << 3;
    unsigned short* dst = vTc + ((size_t)bh * Ddim + d) * Sdim + jt * 64;
    #pragma unroll
    for (int cc = 0; cc < 2; cc++) {
        int tb = (tid & 3) * 16 + cc * 8;
        bf16x8 o;
        #pragma unroll
        for (int i = 0; i < 8; i++) o[i] = (short)T[tb + i][d];
        *(bf16x8*)(dst + (tb ^ xr)) = o;
    }
}

// ================= 8-phase 512-thread MFMA GEMM (T2+T3+T4+T5) =================
// EPI: 1 = fused QKV (rope->bf16), 3 = bias+silu->bf16,
//      5 = plain f32 write at OF + ks*ksStride, 7 = nontemporal f32 write
template <int EPI, int BM, int BN, int WM, int WN>
__global__ __launch_bounds__(512) void gemm8p(
    const unsigned short* __restrict__ A, const unsigned short* __restrict__ Bt,
    float* __restrict__ OF, unsigned short* __restrict__ Hq, unsigned short* __restrict__ Hk,
    unsigned short* __restrict__ Hv, const float* __restrict__ bias,
    const float* __restrict__ cosT, const float* __restrict__ sinT,
    int Kc, int ldK, int ldC, int gridM, int gridN, size_t ksStride) {
    constexpr int MI = BM / WM / 16, NI = BN / WN / 16;
    constexpr int MH = MI / 2, NH = NI / 2;
    constexpr int LA = BM / 128, LB = BN / 128;
    constexpr int HA = BM / WM / 2;   // A half-selector
    constexpr int HB = BN / WN / 2;   // B half-selector
    constexpr int ABUF = BM * 64, BBUF = BN * 64;

    __shared__ unsigned short lds[2 * ABUF + 2 * BBUF];

    int bid = blockIdx.x;
    const int nwg = gridDim.x;
    if ((nwg & 7) == 0) bid = (bid & 7) * (nwg >> 3) + (bid >> 3);   // XCD swizzle (bijective: nwg%8==0)
    const int mn = gridM * gridN;
    const int ks = bid / mn;
    const int rem = bid - ks * mn;
    const int bm = (rem % gridM) * BM;
    const int bn = (rem / gridM) * BN;
    const unsigned short* Ap = A + (size_t)ks * Kc;
    const unsigned short* Bp = Bt + (size_t)ks * Kc;

    const int tid = threadIdx.x;
    const int lane = tid & 63, wid = tid >> 6;
    const int lc = lane & 15, lg = lane >> 4;
    const int wwm = wid / WN, wwn = wid % WN;

    const int srow = tid >> 3;                    // 0..63
    const int scol = ((tid & 7) ^ (srow & 7)) * 8;
    const int ak0 = (lg * 8) ^ ((lc & 7) * 8);
    const int ak1 = (32 + lg * 8) ^ ((lc & 7) * 8);

    f32x4 acc[MI][NI];
    f32x4 zero = {0.0f, 0.0f, 0.0f, 0.0f};
    #pragma unroll
    for (int i = 0; i < MI; i++)
        #pragma unroll
        for (int j = 0; j < NI; j++) acc[i][j] = zero;

    bf16x8 a[MH][2], b0[NH][2], b1[NH][2];

    auto stage_a = [&](int half, int nbuf, int kt) {
        #pragma unroll
        for (int j = 0; j < LA; j++) {
            const int idx = j * 64 + srow;                          // [0, BM/2)
            const int grow = (idx / HA) * (BM / WM) + half * HA + (idx % HA);
            const unsigned short* g = Ap + (size_t)(bm + grow) * ldK + kt + scol;
            GLD16(g, &lds[nbuf * ABUF + half * (ABUF / 2) + (j * 512 + tid) * 8]);
        }
    };
    auto stage_b = [&](int half, int nbuf, int kt) {
        #pragma unroll
        for (int j = 0; j < LB; j++) {
            const int idx = j * 64 + srow;                          // [0, BN/2)
            const int grow = (idx / HB) * (BN / WN) + half * HB + (idx % HB);
            const unsigned short* g = Bp + (size_t)(bn + grow) * ldK + kt + scol;
            GLD16(g, &lds[2 * ABUF + nbuf * BBUF + half * (BBUF / 2) + (j * 512 + tid) * 8]);
        }
    };

#define DS_A(mh_, cur_)                                                                   \
    _Pragma("unroll") for (int m = 0; m < MH; m++) {                                      \
        const int ro = (cur_)*ABUF + (mh_) * (ABUF / 2) + (wwm * HA + m * 16 + lc) * 64;  \
        a[m][0] = *(const bf16x8*)&lds[ro + ak0];                                         \
        a[m][1] = *(const bf16x8*)&lds[ro + ak1];                                         \
    }
#define DS_B(bb_, nh_, cur_)                                                              \
    _Pragma("unroll") for (int n = 0; n < NH; n++) {                                      \
        const int ro = 2 * ABUF + (cur_)*BBUF + (nh_) * (BBUF / 2) + (wwn * HB + n * 16 + lc) * 64; \
        bb_[n][0] = *(const bf16x8*)&lds[ro + ak0];                                       \
        bb_[n][1] = *(const bf16x8*)&lds[ro + ak1];                                       \
    }
#define MFMA_PH(mh_, nh_, bb_)                                                            \
    __builtin_amdgcn_s_setprio(1);                                                        \
    _Pragma("unroll") for (int m = 0; m < MH; m++) _Pragma("unroll") for (int n = 0; n < NH; n++) { \
        acc[(mh_)*MH + m][(nh_)*NH + n] = MFMA16(a[m][0], bb_[n][0], acc[(mh_)*MH + m][(nh_)*NH + n]); \
        acc[(mh_)*MH + m][(nh_)*NH + n] = MFMA16(a[m][1], bb_[n][1], acc[(mh_)*MH + m][(nh_)*NH + n]); \
    }                                                                                     \
    __builtin_amdgcn_s_setprio(0);
#define BAR_PRE()                                                                         \
    __builtin_amdgcn_sched_barrier(0);                                                    \
    __builtin_amdgcn_s_barrier();
#define BAR_END()                                                                         \
    asm volatile("" ::: "memory");                                                        \
    __builtin_amdgcn_s_barrier();                                                         \
    __builtin_amdgcn_sched_barrier(0);

    // prologue: tile 0 half-tiles in steady-state order; leave {Bh1,Ah1} in flight
    stage_a(0, 0, 0);
    stage_b(0, 0, 0);
    stage_b(1, 0, 0);
    stage_a(1, 0, 0);
    vwait<LA + LB>();
    BAR_END();

    const int NT = Kc >> 6;
    for (int t = 0; t < NT; t++) {
        const int cur = t & 1, nxt = cur ^ 1;
        const int ktn = (t + 1 < NT) ? (t + 1) * 64 : t * 64;
        // phase 1: quadrant (0,0)
        DS_A(0, cur);
        DS_B(b0, 0, cur);
        stage_a(0, nxt, ktn);
        BAR_PRE();
        MFMA_PH(0, 0, b0);
        vwait<2 * LA>();            // completes B_h1(cur)
        BAR_END();
        // phase 2: quadrant (0,1)
        DS_B(b1, 1, cur);
        stage_b(0, nxt, ktn);
        BAR_PRE();
        MFMA_PH(0, 1, b1);
        vwait<LA + LB>();           // completes A_h1(cur)
        BAR_END();
        // phase 3: quadrant (1,1)
        DS_A(1, cur);
        stage_b(1, nxt, ktn);
        BAR_PRE();
        MFMA_PH(1, 1, b1);
        BAR_END();
        // phase 4: quadrant (1,0)
        stage_a(1, nxt, ktn);
        BAR_PRE();
        MFMA_PH(1, 0, b0);
        vwait<LA + LB>();           // completes A_h0, B_h0 of nxt
        BAR_END();
    }
    asm volatile("s_waitcnt vmcnt(0)" ::: "memory");   // drain LDS-destined loads before endpgm
#undef DS_A
#undef DS_B
#undef MFMA_PH
#undef BAR_PRE
#undef BAR_END

    // epilogue. D frag layout: row = lg*4 + r, col = lc
    #pragma unroll
    for (int i = 0; i < MI; i++) {
        if (EPI == 1) {
            const int colbase = bn + wwn * (BN / WN);
            const int zc = colbase >> 10;                 // 0=q 1=k 2=v
            unsigned short* OH = (zc == 0) ? Hq : (zc == 1) ? Hk : Hv;
            const int hcol = (colbase >> 6) & 15;
            #pragma unroll
            for (int r = 0; r < 4; r++) {
                int row = bm + wwm * (BM / WM) + i * 16 + lg * 4 + r;
                int b = row >> 10, s = row & 1023;
                size_t base = ((size_t)(b * Hdim + hcol) * Sdim + s) << 6;
                if (zc == 2) {
                    #pragma unroll
                    for (int j = 0; j < 4; j++) OH[base + j * 16 + lc] = f2bf(acc[i][j][r]);
                } else {
                    #pragma unroll
                    for (int j = 0; j < 2; j++) {
                        int d = j * 16 + lc;              // [0,32)
                        float x1 = acc[i][j][r];
                        float x2 = acc[i][j + 2][r];
                        float c = cosT[s * 64 + d];
                        float sn = sinT[s * 64 + d];
                        OH[base + d] = f2bf(x1 * c - x2 * sn);
                        OH[base + d + 32] = f2bf(x2 * c + x1 * sn);
                    }
                }
            }
        } else {
            float* OFk = OF + (size_t)ks * ksStride;
            #pragma unroll
            for (int r = 0; r < 4; r++) {
                int row = bm + wwm * (BM / WM) + i * 16 + lg * 4 + r;
                #pragma unroll
                for (int j = 0; j < NI; j++) {
                    int col = bn + wwn * (BN / WN) + j * 16 + lc;
                    float v = acc[i][j][r];
                    if (EPI == 3) {
                        float t = v + bias[col];
                        Hq[(size_t)row * ldC + col] = f2bf(t / (1.0f + expf(-t)));
                    } else if (EPI == 7) {
                        __builtin_nontemporal_store(v, &OFk[(size_t)row * ldC + col]);
                    } else {
                        OFk[(size_t)row * ldC + col] = v;
                    }
                }
            }
        }
    }
}

// ---------------- flash attention over compacted keys (routed bias) ----------------
// QBLK=128: 8 waves x 16 q-rows; K gathered in-LDS-stage via idxC; V^T pre-gathered.
// T13 defer-max: skip O-rescale when the whole wave's tile-max growth <= 8.
__global__ __launch_bounds__(512) void attn_kernel(const unsigned short* __restrict__ q16,
                                                   const unsigned short* __restrict__ k16,
                                                   const unsigned short* __restrict__ vTc,
                                                   const int* __restrict__ idxC,
                                                   const float* __restrict__ biasC,
                                                   const int* __restrict__ ntA,
                                                   unsigned short* __restrict__ o16) {
    const int qb = blockIdx.x;   // 8 (128 q rows each)
    const int bh = blockIdx.y;   // 32
    const int tid = threadIdx.x;
    const int w = tid >> 6, lane = tid & 63;
    const int lg = lane >> 4, lc = lane & 15;
    const int nt = ntA[bh];

    __shared__ unsigned short Ks[2][64 * 64];
    __shared__ unsigned short Vs[2][64 * 64];
    __shared__ unsigned short Pq[8][16][72];
    __shared__ float sbAll[1024];

    {
        const float2 bv = ((const float2*)(biasC + (size_t)bh * Sdim))[tid];
        *(float2*)&sbAll[tid * 2] = bv;
    }

    const int qrow = qb * 128 + w * 16 + lc;
    const unsigned short* qbase = q16 + ((size_t)bh * Sdim + qrow) * Ddim;
    bf16x8 qf[2];
    qf[0] = *(const bf16x8*)(qbase + lg * 8);
    qf[1] = *(const bf16x8*)(qbase + 32 + lg * 8);

    const int grow = tid >> 3;                 // 0..63
    const int gc = (tid & 7) * 8;
    const int ksw = (grow & 7) << 3;           // K source-col swizzle
    const unsigned short* kbase = k16 + (size_t)bh * Sdim * Ddim;
    const int* ibase = idxC + (size_t)bh * Sdim;
    const unsigned short* vbase = vTc + (size_t)bh * Ddim * Sdim;

    auto stageKV = [&](int buf, int t1) {
        int s0 = ibase[t1 + grow];
        GLD16(kbase + (size_t)s0 * Ddim + (gc ^ ksw), &Ks[buf][tid * 8]);
        GLD16(vbase + (size_t)grow * Sdim + t1 + gc, &Vs[buf][tid * 8]);
    };

    stageKV(0, 0);
    __syncthreads();

    float m_i = -1e30f, l_i = 0.0f;
    f32x4 ot[4];
    f32x4 zero = {0.0f, 0.0f, 0.0f, 0.0f};
    #pragma unroll
    for (int fd = 0; fd < 4; fd++) ot[fd] = zero;

    const int sw = (lc & 7) << 3;

    for (int tt = 0; tt < nt; tt++) {
        const int cur = tt & 1;
        if (tt > 0) {
            asm volatile("s_waitcnt vmcnt(0)" ::: "memory");
            __builtin_amdgcn_sched_barrier(0);
            __builtin_amdgcn_s_barrier();
        }
        if (tt < nt - 1) {
            stageKV(cur ^ 1, (tt + 1) * 64);
        }

        f32x4 sf[4];
        #pragma unroll
        for (int f = 0; f < 4; f++) {
            const int trow = f * 16 + lc;
            f32x4 a = zero;
            #pragma unroll
            for (int ks = 0; ks < 2; ks++) {
                bf16x8 kfr = *(bf16x8*)&Ks[cur][trow * 64 + ((ks * 32 + lg * 8) ^ sw)];
                a = MFMA16(kfr, qf[ks], a);
            }
            sf[f] = a;
        }
        const int t0 = tt * 64;
        float tmax = -1e30f;
        #pragma unroll
        for (int f = 0; f < 4; f++)
            #pragma unroll
            for (int j = 0; j < 4; j++) {
                float v = sf[f][j] * 0.125f + sbAll[t0 + f * 16 + lg * 4 + j];
                sf[f][j] = v;
                tmax = fmaxf(tmax, v);
            }
        tmax = fmaxf(tmax, __shfl_xor(tmax, 16));
        tmax = fmaxf(tmax, __shfl_xor(tmax, 32));
        // T13 defer-max: rescale only when some lane's max grew by > 8
        if (!__all(tmax - m_i <= 8.0f)) {
            float mnew = fmaxf(m_i, tmax);
            float alpha = expf(m_i - mnew);
            l_i *= alpha;
            #pragma unroll
            for (int fd = 0; fd < 4; fd++)
                #pragma unroll
                for (int j = 0; j < 4; j++) ot[fd][j] *= alpha;
            m_i = mnew;
        }
        float lsum = 0.0f;
        #pragma unroll
        for (int f = 0; f < 4; f++)
            #pragma unroll
            for (int j = 0; j < 4; j++) {
                float p = expf(sf[f][j] - m_i);
                sf[f][j] = p;
                lsum += p;
            }
        lsum += __shfl_xor(lsum, 16);
        lsum += __shfl_xor(lsum, 32);
        l_i += lsum;
        #pragma unroll
        for (int f = 0; f < 4; f++) {
            short4 ps = make_short4((short)f2bf(sf[f][0]), (short)f2bf(sf[f][1]),
                                    (short)f2bf(sf[f][2]), (short)f2bf(sf[f][3]));
            *(short4*)&Pq[w][lc][f * 16 + lg * 4] = ps;
        }
        #pragma unroll
        for (int ks = 0; ks < 2; ks++) {
            bf16x8 pf = *(bf16x8*)&Pq[w][lc][ks * 32 + lg * 8];
            #pragma unroll
            for (int fd = 0; fd < 4; fd++) {
                bf16x8 vfr = *(bf16x8*)&Vs[cur][(fd * 16 + lc) * 64 + ((ks * 32 + lg * 8) ^ sw)];
                ot[fd] = MFMA16(vfr, pf, ot[fd]);
            }
        }
    }
    asm volatile("s_waitcnt vmcnt(0)" ::: "memory");   // drain LDS-destined loads before endpgm
    float rl = 1.0f / l_i;
    int b = bh >> 4, h = bh & 15;
    #pragma unroll
    for (int fd = 0; fd < 4; fd++)
        #pragma unroll
        for (int j = 0; j < 4; j++) {
            int d = fd * 16 + lg * 4 + j;
            o16[((size_t)b * Sdim + qrow) * HDdim + h * 64 + d] = f2bf(ot[fd][j] * rl);
        }
}

extern "C" void kernel_launch(void* const* d_in, const int* in_sizes, int n_in,
                              void* d_out, int out_size, void* d_ws, size_t ws_size,
                              hipStream_t stream) {
    const int* ids = (const int*)d_in[0];
    const float* amask = (const float*)d_in[1];
    const float* emb = (const float*)d_in[2];
    const float* ln1w = (const float*)d_in[3];
    const float* ln1b = (const float*)d_in[4];
    const float* Wq = (const float*)d_in[5];
    const float* Wk = (const float*)d_in[6];
    const float* Wv = (const float*)d_in[7];
    const float* Wo = (const float*)d_in[8];
    const float* Wr = (const float*)d_in[9];
    const float* ln2w = (const float*)d_in[10];
    const float* ln2b = (const float*)d_in[11];
    const float* W1 = (const float*)d_in[12];
    const float* b1 = (const float*)d_in[13];
    const float* W2 = (const float*)d_in[14];
    const float* b2 = (const float*)d_in[15];
    const float* nw = (const float*)d_in[16];
    const float* nb = (const float*)d_in[17];
    const float* lmh = (const float*)d_in[18];
    float* out = (float*)d_out;

    char* p = (char*)d_ws;
    size_t off = 0;
    auto alloc = [&](size_t bytes) -> void* {
        void* r = p + off;
        off += (bytes + 255) & ~(size_t)255;
        return r;
    };
    float* cosT = (float*)alloc((size_t)Sdim * Ddim * 4);
    float* sinT = (float*)alloc((size_t)Sdim * Ddim * 4);
    float* x = (float*)alloc((size_t)BSdim * HDdim * 4);
    unsigned short* h16 = (unsigned short*)alloc((size_t)BSdim * HDdim * 2);
    unsigned short* o16 = (unsigned short*)alloc((size_t)BSdim * HDdim * 2);
    unsigned short* m16 = (unsigned short*)alloc((size_t)BSdim * Idim * 2);
    unsigned short* q16 = (unsigned short*)alloc((size_t)Bdim * Hdim * Sdim * Ddim * 2);
    unsigned short* k16 = (unsigned short*)alloc((size_t)Bdim * Hdim * Sdim * Ddim * 2);
    unsigned short* v16 = (unsigned short*)alloc((size_t)Bdim * Hdim * Sdim * Ddim * 2);
    unsigned short* vTc = (unsigned short*)alloc((size_t)Bdim * Hdim * Sdim * Ddim * 2);
    float* router = (float*)alloc((size_t)Bdim * Hdim * Sdim * 4);
    float* biasC = (float*)alloc((size_t)Bdim * Hdim * Sdim * 4);
    int* idxC = (int*)alloc((size_t)Bdim * Hdim * Sdim * 4);
    int* ntA = (int*)alloc((size_t)Bdim * Hdim * 4);
    float* po = (float*)alloc((size_t)2 * BSdim * HDdim * 4);   // Wo split-K partials
    float* pw = (float*)alloc((size_t)4 * BSdim * HDdim * 4);   // W2 split-K partials
    unsigned short* wts = (unsigned short*)alloc((size_t)Vdim * HDdim * 2);        // 64MB lm_head
    unsigned short* wtsL = (unsigned short*)alloc((size_t)Ldim * 12 * (1u << 20) * 2);  // 96MB layer weights

    const size_t M1 = 1u << 20;  // 1M elems
    const size_t PS = (size_t)BSdim * HDdim;

    init_kernel<<<BSdim + 256, 256, 0, stream>>>(ids, emb, x, cosT, sinT);
    tconv_all<<<49152 + 32000, 256, 0, stream>>>(Wq, Wk, Wv, Wo, W1, W2, lmh, wtsL, wts);

    for (int l = 0; l < Ldim; l++) {
        unsigned short* wl = wtsL + (size_t)l * 12 * M1;
        const float* Wr_l = Wr + (size_t)l * HDdim * Hdim;
        const float* b1_l = b1 + (size_t)l * Idim;
        const float* b2_l = b2 + (size_t)l * HDdim;

        // ln1 (+fused router). For l>0 it also folds in prev layer's W2 partials + b2.
        if (l == 0)
            ln_kernel<0><<<BSdim, 256, 0, stream>>>(x, nullptr, nullptr, 0, nullptr,
                                                    ln1w + l * HDdim, ln1b + l * HDdim, h16, Wr_l, router);
        else
            ln_kernel<4><<<BSdim, 256, 0, stream>>>(x, x, pw, PS, b2 + (size_t)(l - 1) * HDdim,
                                                    ln1w + l * HDdim, ln1b + l * HDdim, h16, Wr_l, router);
        topk_kernel<<<Bdim * Hdim, 1024, 0, stream>>>(router, amask, biasC, idxC, ntA);
        // fused QKV GEMM (8-phase, 128x128): grid 16 x 24 = 384
        gemm8p<1, 128, 128, 4, 2><<<384, 512, 0, stream>>>(h16, wl, nullptr, q16, k16, v16,
                                                           nullptr, cosT, sinT, HDdim, HDdim, 0, 16, 24, 0);
        // compacted V^T gather; K gathered in-attn
        vgather_kernel<<<dim3(16, 32), 256, 0, stream>>>(v16, idxC, ntA, vTc);
        // attention: QBLK=128, 8 waves
        attn_kernel<<<dim3(8, 32), 512, 0, stream>>>(q16, k16, vTc, idxC, biasC, ntA, o16);
        // Wo GEMM (split-K=2 partial buffers): grid 16 x 8 x 2 = 256
        gemm8p<5, 128, 128, 4, 2><<<256, 512, 0, stream>>>(o16, wl + 3 * M1, po, nullptr, nullptr, nullptr,
                                                           nullptr, nullptr, nullptr, 512, HDdim, HDdim, 16, 8, PS);
        // ln2 folds in Wo partials (x += po0+po1) and LNs the result
        ln_kernel<2><<<BSdim, 256, 0, stream>>>(x, x, po, PS, nullptr,
                                                ln2w + l * HDdim, ln2b + l * HDdim, h16, nullptr, nullptr);
        // W1 GEMM (bias+silu): grid 16 x 32 = 512
        gemm8p<3, 128, 128, 4, 2><<<512, 512, 0, stream>>>(h16, wl + 4 * M1, nullptr, m16, nullptr, nullptr,
                                                           b1_l, nullptr, nullptr, HDdim, HDdim, Idim, 16, 32, 0);
        // W2 GEMM (split-K=4 partial buffers): grid 16 x 8 x 4 = 512
        gemm8p<5, 128, 128, 4, 2><<<512, 512, 0, stream>>>(m16, wl + 8 * M1, pw, nullptr, nullptr, nullptr,
                                                           nullptr, nullptr, nullptr, 1024, Idim, HDdim, 16, 8, PS);
    }

    // final ln folds in last layer's W2 partials + b2
    ln_kernel<4><<<BSdim, 256, 0, stream>>>(x, nullptr, pw, PS, b2 + (size_t)3 * HDdim,
                                            nw, nb, h16, nullptr, nullptr);
    // lm_head: 256x256 (measured-best config), single dispatch, nt stores
    gemm8p<7, 256, 256, 2, 4><<<1000, 512, 0, stream>>>(h16, wts, out, nullptr, nullptr, nullptr,
                                                        nullptr, nullptr, nullptr, HDdim, HDdim, Vdim, 8, 125, 0);
}